// Round 3
// baseline (1587.035 us; speedup 1.0000x reference)
//
#include <hip/hip_runtime.h>
#include <hip/hip_bf16.h>
#include <stdint.h>

#define IN_DIM 256
#define HIDDEN 256
#define EMBED 128

using bf16x8 = __attribute__((ext_vector_type(8))) short;   // 8 bf16 in 4 VGPRs
using f32x4  = __attribute__((ext_vector_type(4))) float;

// ---------------------------------------------------------------------------
// Split fp32 -> (hi, lo) bf16 pair, RNE both times.  x ~= hi + lo.
// ---------------------------------------------------------------------------
__device__ inline void split_bf16(float x, unsigned short& hb, unsigned short& lb)
{
    unsigned int u = __float_as_uint(x);
    unsigned int r = u + 0x7fffu + ((u >> 16) & 1u);
    hb = (unsigned short)(r >> 16);
    float fh = __uint_as_float((unsigned int)hb << 16);
    float xl = x - fh;
    unsigned int ul = __float_as_uint(xl);
    unsigned int rl = ul + 0x7fffu + ((ul >> 16) & 1u);
    lb = (unsigned short)(rl >> 16);
}

// Pre-split a weight matrix into bf16 hi/lo planes (tiny: 64K elems).
__global__ __launch_bounds__(256) void conv_w(
    const float* __restrict__ src, unsigned short* __restrict__ hi,
    unsigned short* __restrict__ lo, int n)
{
    const int i = blockIdx.x * 256 + threadIdx.x;
    if (i < n) {
        unsigned short hb, lb;
        split_bf16(src[i], hb, lb);
        hi[i] = hb; lo[i] = lb;
    }
}

// ---------------------------------------------------------------------------
// Fused output GEMM:
//   out = relu( aggP @ Wp^T + aggN @ Wn^T + h @ Ws^T
//               + sw_pos*b_pos + sw_neg*b_neg + b_self )
// K = 3 segments x 256.  MFMA 16x16x32 bf16, split-bf16 3-term for fp32 acc.
// Block: 256 thr = 4 waves; BM=64 (wave owns 16 rows), BN=256 (16 n-frags).
// A fragments read from global fp32 and split in-register (L1-hot across waves).
// ---------------------------------------------------------------------------
__global__ __launch_bounds__(256) void mega_gemm(
    const float* __restrict__ aggP, const float* __restrict__ aggN,
    const float* __restrict__ h,
    const unsigned short* __restrict__ Whi, const unsigned short* __restrict__ Wlo,
    const float* __restrict__ b_pos, const float* __restrict__ b_neg,
    const float* __restrict__ b_self,
    const float* __restrict__ sw_pos, const float* __restrict__ sw_neg,
    float* __restrict__ out, int M)
{
    const int tid  = threadIdx.x;
    const int lane = tid & 63;
    const int wid  = tid >> 6;
    const int lr   = lane & 15;   // A row / B col / C col within fragment
    const int lg   = lane >> 4;   // k-group
    const int m0   = blockIdx.x * 64;

    const int rowA = min(m0 + wid * 16 + lr, M - 1);
    const float* As[3] = {aggP, aggN, h};

    f32x4 acc[16];
#pragma unroll
    for (int i = 0; i < 16; ++i) acc[i] = (f32x4){0.f, 0.f, 0.f, 0.f};

#pragma unroll
    for (int seg = 0; seg < 3; ++seg) {
        const float* A = As[seg] + (size_t)rowA * 256;
        const unsigned short* WH = Whi + seg * 65536;
        const unsigned short* WL = Wlo + seg * 65536;
        for (int ks = 0; ks < 8; ++ks) {
            const int kc = ks * 32 + lg * 8;
            const float4 x0 = *(const float4*)(A + kc);
            const float4 x1 = *(const float4*)(A + kc + 4);
            const float xs[8] = {x0.x, x0.y, x0.z, x0.w, x1.x, x1.y, x1.z, x1.w};
            bf16x8 ah, al;
#pragma unroll
            for (int j = 0; j < 8; ++j) {
                unsigned short hb, lb;
                split_bf16(xs[j], hb, lb);
                ah[j] = (short)hb;
                al[j] = (short)lb;
            }
#pragma unroll
            for (int nf = 0; nf < 16; ++nf) {
                const size_t wo = (size_t)(nf * 16 + lr) * 256 + kc;
                const bf16x8 bh = *(const bf16x8*)(WH + wo);
                const bf16x8 bl = *(const bf16x8*)(WL + wo);
                acc[nf] = __builtin_amdgcn_mfma_f32_16x16x32_bf16(ah, bh, acc[nf], 0, 0, 0);
                acc[nf] = __builtin_amdgcn_mfma_f32_16x16x32_bf16(ah, bl, acc[nf], 0, 0, 0);
                acc[nf] = __builtin_amdgcn_mfma_f32_16x16x32_bf16(al, bh, acc[nf], 0, 0, 0);
            }
        }
    }

    // epilogue: bias (weighted by sw sums) + ReLU, write once
    float bp[16], bn[16], bs[16];
#pragma unroll
    for (int nf = 0; nf < 16; ++nf) {
        const int col = nf * 16 + lr;
        bp[nf] = b_pos[col]; bn[nf] = b_neg[col]; bs[nf] = b_self[col];
    }
#pragma unroll
    for (int i = 0; i < 4; ++i) {
        const int r = m0 + wid * 16 + lg * 4 + i;
        if (r < M) {
            const float swp = sw_pos[r], swn = sw_neg[r];
#pragma unroll
            for (int nf = 0; nf < 16; ++nf) {
                const int col = nf * 16 + lr;
                const float v = acc[nf][i] + swp * bp[nf] + swn * bn[nf] + bs[nf];
                out[(size_t)r * 256 + col] = fmaxf(v, 0.f);
            }
        }
    }
}

// ---------------------------------------------------------------------------
// GEMM: C[M,N] = A[M,K] @ B[K,N] (fp32, no transpose/bias) — U = emb @ W_u
// ---------------------------------------------------------------------------
__global__ __launch_bounds__(256) void gemm_nn(
    const float* __restrict__ A, const float* __restrict__ B,
    float* __restrict__ C, int M, int N, int K)
{
    __shared__ float Ast[16][68];
    __shared__ float Bs[16][68];
    const int tid = threadIdx.x;
    const int tx = tid & 15, ty = tid >> 4;
    const int m0 = blockIdx.x * 64, n0 = blockIdx.y * 64;

    const int lm = tid >> 2;
    const int lk = (tid & 3) << 2;
    const int bk = tid >> 4;
    const int bn = (tid & 15) << 2;

    float acc[4][4] = {};

    for (int k0 = 0; k0 < K; k0 += 16) {
        float4 av = make_float4(0.f, 0.f, 0.f, 0.f);
        const int am = m0 + lm;
        if (am < M) av = *(const float4*)&A[(size_t)am * K + k0 + lk];
        const float4 bvl = *(const float4*)&B[(size_t)(k0 + bk) * N + n0 + bn];
        __syncthreads();
        Ast[lk + 0][lm] = av.x; Ast[lk + 1][lm] = av.y;
        Ast[lk + 2][lm] = av.z; Ast[lk + 3][lm] = av.w;
        *(float4*)&Bs[bk][bn] = bvl;
        __syncthreads();
#pragma unroll
        for (int k = 0; k < 16; ++k) {
            const float4 a = *(const float4*)&Ast[k][ty * 4];
            const float4 b = *(const float4*)&Bs[k][tx * 4];
            acc[0][0] += a.x * b.x; acc[0][1] += a.x * b.y; acc[0][2] += a.x * b.z; acc[0][3] += a.x * b.w;
            acc[1][0] += a.y * b.x; acc[1][1] += a.y * b.y; acc[1][2] += a.y * b.z; acc[1][3] += a.y * b.w;
            acc[2][0] += a.z * b.x; acc[2][1] += a.z * b.y; acc[2][2] += a.z * b.z; acc[2][3] += a.z * b.w;
            acc[3][0] += a.w * b.x; acc[3][1] += a.w * b.y; acc[3][2] += a.w * b.z; acc[3][3] += a.w * b.w;
        }
    }

#pragma unroll
    for (int i = 0; i < 4; ++i) {
        const int m = m0 + ty * 4 + i;
        if (m < M) {
            float4 o;
            o.x = acc[i][0]; o.y = acc[i][1]; o.z = acc[i][2]; o.w = acc[i][3];
            *(float4*)&C[(size_t)m * N + n0 + tx * 4] = o;
        }
    }
}

// ---------------------------------------------------------------------------
// Finsler edge weight, one wave per edge.
// ---------------------------------------------------------------------------
__global__ __launch_bounds__(256) void edge_weight(
    const float* __restrict__ emb, const float* __restrict__ U,
    const float* __restrict__ w_beta, const float* __restrict__ alpha_p,
    const int* __restrict__ src, const int* __restrict__ dst,
    float* __restrict__ w_out, int E)
{
    const int wv = (int)((blockIdx.x * (size_t)blockDim.x + threadIdx.x) >> 6);
    const int lane = threadIdx.x & 63;
    if (wv >= E) return;
    const int s = src[wv], d = dst[wv];

    const float* xj = emb + (size_t)s * EMBED;
    const float* xi = emb + (size_t)d * EMBED;
    const float* uj = U + (size_t)s * EMBED;

    const float xj0 = xj[lane], xj1 = xj[lane + 64];
    const float xi0 = xi[lane], xi1 = xi[lane + 64];
    const float u0 = uj[lane],  u1 = uj[lane + 64];
    const float wb0 = w_beta[lane], wb1 = w_beta[lane + 64];

    const float d0 = xi0 - xj0, d1 = xi1 - xj1;
    float pe = d0 * d0 + d1 * d1;
    float pa = d0 * u0 + d1 * u1;
    float pb = xj0 * wb0 + xj1 * wb1;

#pragma unroll
    for (int off = 32; off > 0; off >>= 1) {
        pe += __shfl_xor(pe, off);
        pa += __shfl_xor(pa, off);
        pb += __shfl_xor(pb, off);
    }

    if (lane == 0) {
        const float alpha = fminf(fmaxf(alpha_p[0], 0.1f), 10.0f);
        const float beta = tanhf(pb);
        const float dist = sqrtf(pe) + beta * pa;
        w_out[wv] = expf(-alpha * fmaxf(dist, 0.0f));
    }
}

// ---------------------------------------------------------------------------
// CSR-by-dst build: zero -> hist -> scan(3) -> place
// ---------------------------------------------------------------------------
__global__ __launch_bounds__(256) void zero_int(int* __restrict__ p, int n)
{
    const int i = blockIdx.x * blockDim.x + threadIdx.x;
    if (i < n) p[i] = 0;
}

__global__ __launch_bounds__(256) void hist(
    const int* __restrict__ dst, int* __restrict__ counts, int E)
{
    const int e = blockIdx.x * blockDim.x + threadIdx.x;
    if (e < E) atomicAdd(&counts[dst[e]], 1);
}

__global__ __launch_bounds__(256) void scan1(
    const int* __restrict__ counts, int* __restrict__ offs,
    int* __restrict__ bsum, int n)
{
    __shared__ int wsum[4];
    const int t = threadIdx.x;
    const int gi = blockIdx.x * 1024 + t * 4;
    int v[4];
#pragma unroll
    for (int j = 0; j < 4; ++j) v[j] = (gi + j < n) ? counts[gi + j] : 0;
    const int local = v[0] + v[1] + v[2] + v[3];
    const int lane = t & 63;
    int x = local;
#pragma unroll
    for (int off = 1; off < 64; off <<= 1) {
        const int y = __shfl_up(x, off);
        if (lane >= off) x += y;
    }
    if (lane == 63) wsum[t >> 6] = x;
    __syncthreads();
    int woff = 0;
    const int wid = t >> 6;
    for (int w = 0; w < wid; ++w) woff += wsum[w];
    int run = woff + x - local;
#pragma unroll
    for (int j = 0; j < 4; ++j) {
        if (gi + j < n) offs[gi + j] = run;
        run += v[j];
    }
    if (t == 255) bsum[blockIdx.x] = woff + x;
}

__global__ __launch_bounds__(128) void scan2(int* __restrict__ bsum, int nb)
{
    __shared__ int tmp[128];
    const int t = threadIdx.x;
    tmp[t] = (t < nb) ? bsum[t] : 0;
    __syncthreads();
    if (t < nb) {
        int s = 0;
        for (int i = 0; i < t; ++i) s += tmp[i];
        bsum[t] = s;
    }
}

__global__ __launch_bounds__(256) void scan3(
    int* __restrict__ offs, int* __restrict__ cur,
    const int* __restrict__ bsum, int n, int E)
{
    const int gi = blockIdx.x * blockDim.x + threadIdx.x;
    if (gi < n) {
        const int v = offs[gi] + bsum[gi >> 10];
        offs[gi] = v;
        cur[gi] = v;
    }
    if (gi == 0) offs[n] = E;
}

__global__ __launch_bounds__(256) void place(
    const int* __restrict__ src, const int* __restrict__ dst,
    const float* __restrict__ w, int* __restrict__ cur,
    int* __restrict__ esrc, float* __restrict__ ew, int E)
{
    const int e = blockIdx.x * blockDim.x + threadIdx.x;
    if (e < E) {
        const int p = atomicAdd(&cur[dst[e]], 1);
        esrc[p] = src[e];
        ew[p] = w[e];
    }
}

// ---------------------------------------------------------------------------
// Gather in h-space (linearity trick): agg[node] = sum_e w_e * h[src_e],
// sw[node] = sum_e w_e.  Pure write (no RMW).
// ---------------------------------------------------------------------------
__global__ __launch_bounds__(256) void gather_h(
    const float* __restrict__ h, const int* __restrict__ offs,
    const int* __restrict__ esrc, const float* __restrict__ ew,
    float* __restrict__ agg, float* __restrict__ sw, int n)
{
    const int node = (int)((blockIdx.x * (size_t)blockDim.x + threadIdx.x) >> 6);
    const int lane = threadIdx.x & 63;
    if (node >= n) return;
    const int s0 = offs[node], s1 = offs[node + 1];

    float4 acc = make_float4(0.f, 0.f, 0.f, 0.f);
    float s = 0.f;
    for (int k = s0; k < s1; ++k) {
        const int sr = esrc[k];
        const float wv = ew[k];
        const float4 v = *(const float4*)&h[(size_t)sr * IN_DIM + lane * 4];
        acc.x += v.x * wv; acc.y += v.y * wv;
        acc.z += v.z * wv; acc.w += v.w * wv;
        s += wv;
    }

    *(float4*)&agg[(size_t)node * IN_DIM + lane * 4] = acc;
    if (lane == 0) sw[node] = s;
}

// ---------------------------------------------------------------------------
extern "C" void kernel_launch(void* const* d_in, const int* in_sizes, int n_in,
                              void* d_out, int out_size, void* d_ws, size_t ws_size,
                              hipStream_t stream)
{
    const float* h        = (const float*)d_in[0];
    const int*   pos_src  = (const int*)d_in[1];
    const int*   pos_dst  = (const int*)d_in[2];
    const int*   neg_src  = (const int*)d_in[3];
    const int*   neg_dst  = (const int*)d_in[4];
    const float* emb      = (const float*)d_in[5];
    const float* W_pos    = (const float*)d_in[6];
    const float* b_pos    = (const float*)d_in[7];
    const float* W_neg    = (const float*)d_in[8];
    const float* b_neg    = (const float*)d_in[9];
    const float* W_self   = (const float*)d_in[10];
    const float* b_self   = (const float*)d_in[11];
    const float* w_pos_b  = (const float*)d_in[12];
    const float* W_pos_u  = (const float*)d_in[13];
    const float* alpha_p  = (const float*)d_in[14];
    const float* w_neg_b  = (const float*)d_in[15];
    const float* W_neg_u  = (const float*)d_in[16];
    const float* alpha_n  = (const float*)d_in[17];
    float* out = (float*)d_out;

    const int n_nodes = in_sizes[0] / IN_DIM;   // 100000
    const int E       = in_sizes[1];            // 500000

    // Workspace layout (everything 16B-aligned by construction).
    float* ws    = (float*)d_ws;
    float* aggP  = ws;                            // [N*256] (doubles as Ubuf in phase 1)
    float* aggN  = aggP + (size_t)n_nodes * 256;  // [N*256]
    float* wpos  = aggN + (size_t)n_nodes * 256;  // [E]
    float* wneg  = wpos + E;                      // [E]
    float* swp   = wneg + E;                      // [N]
    float* swn   = swp + n_nodes;                 // [N]
    int*   counts = (int*)(swn + n_nodes);        // [N]
    int*   offs   = counts + n_nodes;             // [N+4] (padded for alignment)
    int*   cur    = offs + n_nodes + 4;           // [N]
    int*   bsum   = cur + n_nodes;                // [128]
    int*   esrc   = bsum + 128;                   // [E]
    float* ew     = (float*)(esrc + E);           // [E]
    unsigned short* Whi = (unsigned short*)(ew + E);   // [3*256*256]
    unsigned short* Wlo = Whi + 3 * 65536;             // [3*256*256]
    float* Ubuf  = aggP;                          // phase-1 overlap

    const dim3 blk(256);
    const dim3 gU((n_nodes + 63) / 64, EMBED / 64);
    const dim3 gE((E + 3) / 4);                   // wave-per-edge
    const dim3 gEt((E + 255) / 256);              // thread-per-edge
    const dim3 gN((n_nodes + 255) / 256);         // thread-per-node
    const dim3 gW((n_nodes + 3) / 4);             // wave-per-node
    const dim3 gG((n_nodes + 63) / 64);           // mega-GEMM blocks
    const int  nb = (n_nodes + 1023) / 1024;

    // --- Weight split (tiny) ---
    conv_w<<<256, blk, 0, stream>>>(W_pos,  Whi,             Wlo,             65536);
    conv_w<<<256, blk, 0, stream>>>(W_neg,  Whi + 65536,     Wlo + 65536,     65536);
    conv_w<<<256, blk, 0, stream>>>(W_self, Whi + 2 * 65536, Wlo + 2 * 65536, 65536);

    // --- Phase 1: edge weights (Ubuf overlaps aggP; finishes before gathers) ---
    gemm_nn<<<gU, blk, 0, stream>>>(emb, W_pos_u, Ubuf, n_nodes, EMBED, EMBED);
    edge_weight<<<gE, blk, 0, stream>>>(emb, Ubuf, w_pos_b, alpha_p,
                                        pos_src, pos_dst, wpos, E);
    gemm_nn<<<gU, blk, 0, stream>>>(emb, W_neg_u, Ubuf, n_nodes, EMBED, EMBED);
    edge_weight<<<gE, blk, 0, stream>>>(emb, Ubuf, w_neg_b, alpha_n,
                                        neg_src, neg_dst, wneg, E);

    // --- Phase 2: pos CSR + gather into aggP/swp ---
    zero_int<<<gN, blk, 0, stream>>>(counts, n_nodes);
    hist<<<gEt, blk, 0, stream>>>(pos_dst, counts, E);
    scan1<<<nb, blk, 0, stream>>>(counts, offs, bsum, n_nodes);
    scan2<<<1, 128, 0, stream>>>(bsum, nb);
    scan3<<<gN, blk, 0, stream>>>(offs, cur, bsum, n_nodes, E);
    place<<<gEt, blk, 0, stream>>>(pos_src, pos_dst, wpos, cur, esrc, ew, E);
    gather_h<<<gW, blk, 0, stream>>>(h, offs, esrc, ew, aggP, swp, n_nodes);

    // --- Phase 3: neg CSR + gather into aggN/swn ---
    zero_int<<<gN, blk, 0, stream>>>(counts, n_nodes);
    hist<<<gEt, blk, 0, stream>>>(neg_dst, counts, E);
    scan1<<<nb, blk, 0, stream>>>(counts, offs, bsum, n_nodes);
    scan2<<<1, 128, 0, stream>>>(bsum, nb);
    scan3<<<gN, blk, 0, stream>>>(offs, cur, bsum, n_nodes, E);
    place<<<gEt, blk, 0, stream>>>(neg_src, neg_dst, wneg, cur, esrc, ew, E);
    gather_h<<<gW, blk, 0, stream>>>(h, offs, esrc, ew, aggN, swn, n_nodes);

    // --- Phase 4: single fused MFMA GEMM + bias + ReLU ---
    mega_gemm<<<gG, blk, 0, stream>>>(aggP, aggN, h, Whi, Wlo,
                                      b_pos, b_neg, b_self, swp, swn,
                                      out, n_nodes);
}

// Round 5
// 1245.596 us; speedup vs baseline: 1.2741x; 1.2741x over previous
//
#include <hip/hip_runtime.h>
#include <hip/hip_bf16.h>
#include <stdint.h>

#define IN_DIM 256
#define HIDDEN 256
#define EMBED 128

typedef _Float16 f16x8 __attribute__((ext_vector_type(8)));
using f32x4 = __attribute__((ext_vector_type(4))) float;

#define ALD 36   // A LDS row stride in fp32 (32 + 4 pad) -> 144 B, 16B-aligned
#define BLD 40   // B LDS row stride in fp16 (32 + 8 pad) -> 80 B, 16B-aligned

// ---------------------------------------------------------------------------
// Convert the three torch-Linear W [256,256] fp32 into one fp16 plane
// Whf[n][768] with K concatenated as [W_pos | W_neg | W_self].
// ---------------------------------------------------------------------------
__global__ __launch_bounds__(256) void conv_w_f16(
    const float* __restrict__ Wp, const float* __restrict__ Wn,
    const float* __restrict__ Ws, _Float16* __restrict__ Whf)
{
    const int i = blockIdx.x * 256 + threadIdx.x;   // 0 .. 196607
    if (i < 3 * 65536) {
        const int seg = i >> 16;
        const int r   = i & 65535;
        const int n   = r >> 8;
        const int k   = r & 255;
        const float* W = (seg == 0) ? Wp : (seg == 1) ? Wn : Ws;
        Whf[(size_t)n * 768 + seg * 256 + k] = (_Float16)W[n * 256 + k];
    }
}

// ---------------------------------------------------------------------------
// Fused output GEMM (LDS-tiled, prefetched):
//   out = relu( [aggP|aggN|h] @ Whf^T + sw_pos*b_pos + sw_neg*b_neg + b_self )
// BM=128, BN=256 (full width), K=768 = 24 steps of 32.
// 4 waves; wave owns 32 rows x 256 cols: 2 m-frags x 16 n-frags.
// A fp32 in LDS, split to fp16 hi/lo in-register; 2-term MFMA (ah*bh + al*bh).
// ---------------------------------------------------------------------------
__global__ __launch_bounds__(256, 2) void mega_gemm(
    const float* __restrict__ aggP, const float* __restrict__ aggN,
    const float* __restrict__ h,
    const _Float16* __restrict__ Whf,
    const float* __restrict__ b_pos, const float* __restrict__ b_neg,
    const float* __restrict__ b_self,
    const float* __restrict__ sw_pos, const float* __restrict__ sw_neg,
    float* __restrict__ out, int M)
{
    __shared__ float    As[128 * ALD];   // 18432 B
    __shared__ _Float16 Bs[256 * BLD];   // 20480 B

    const int tid  = threadIdx.x;
    const int lane = tid & 63;
    const int wid  = tid >> 6;
    const int lr   = lane & 15;
    const int lg   = lane >> 4;
    const int m0   = blockIdx.x * 128;

    f32x4 acc[2][16];
#pragma unroll
    for (int mf = 0; mf < 2; ++mf)
#pragma unroll
        for (int nf = 0; nf < 16; ++nf) acc[mf][nf] = (f32x4){0.f, 0.f, 0.f, 0.f};

    float4 areg[4];
    int4   breg[4];

    // ---- stage_load(kk): global -> regs ----
    auto stage_load = [&](int kk) {
        const int seg  = kk >> 3;          // 8 K-steps per 256-col segment
        const int kloc = (kk & 7) * 32;
        const float* A = (seg == 0) ? aggP : (seg == 1) ? aggN : h;
#pragma unroll
        for (int i = 0; i < 4; ++i) {
            const int c   = tid + 256 * i;
            const int row = c >> 3;
            const int rg  = min(m0 + row, M - 1);
            areg[i] = *(const float4*)&A[(size_t)rg * 256 + kloc + (c & 7) * 4];
        }
        const int kg = kk * 32;
#pragma unroll
        for (int i = 0; i < 4; ++i) {
            const int c = tid + 256 * i;
            const int n = c >> 2;
            breg[i] = *(const int4*)&Whf[(size_t)n * 768 + kg + (c & 3) * 8];
        }
    };

    stage_load(0);

    for (int kk = 0; kk < 24; ++kk) {
        __syncthreads();                       // LDS consumers of prev step done
#pragma unroll
        for (int i = 0; i < 4; ++i) {
            const int c   = tid + 256 * i;
            const int row = c >> 3;
            *(float4*)&As[row * ALD + (c & 7) * 4] = areg[i];
        }
#pragma unroll
        for (int i = 0; i < 4; ++i) {
            const int c = tid + 256 * i;
            const int n = c >> 2;
            *(int4*)&Bs[n * BLD + (c & 3) * 8] = breg[i];
        }
        __syncthreads();

        if (kk < 23) stage_load(kk + 1);       // prefetch overlaps compute

        // ---- compute this K-step from LDS ----
        f16x8 ah[2], al[2];
#pragma unroll
        for (int mf = 0; mf < 2; ++mf) {
            const int row = wid * 32 + mf * 16 + lr;
            const float4 x0 = *(const float4*)&As[row * ALD + lg * 8];
            const float4 x1 = *(const float4*)&As[row * ALD + lg * 8 + 4];
            const float xs[8] = {x0.x, x0.y, x0.z, x0.w, x1.x, x1.y, x1.z, x1.w};
#pragma unroll
            for (int j = 0; j < 8; ++j) {
                const _Float16 hi = (_Float16)xs[j];
                ah[mf][j] = hi;
                al[mf][j] = (_Float16)(xs[j] - (float)hi);
            }
        }
#pragma unroll
        for (int nf = 0; nf < 16; ++nf) {
            const f16x8 bh = *(const f16x8*)&Bs[(nf * 16 + lr) * BLD + lg * 8];
            acc[0][nf] = __builtin_amdgcn_mfma_f32_16x16x32_f16(ah[0], bh, acc[0][nf], 0, 0, 0);
            acc[0][nf] = __builtin_amdgcn_mfma_f32_16x16x32_f16(al[0], bh, acc[0][nf], 0, 0, 0);
            acc[1][nf] = __builtin_amdgcn_mfma_f32_16x16x32_f16(ah[1], bh, acc[1][nf], 0, 0, 0);
            acc[1][nf] = __builtin_amdgcn_mfma_f32_16x16x32_f16(al[1], bh, acc[1][nf], 0, 0, 0);
        }
    }

    // ---- epilogue: weighted bias + ReLU, single write ----
#pragma unroll
    for (int nf = 0; nf < 16; ++nf) {
        const int col = nf * 16 + lr;
        const float bpv = b_pos[col], bnv = b_neg[col], bsv = b_self[col];
#pragma unroll
        for (int mf = 0; mf < 2; ++mf) {
#pragma unroll
            for (int i = 0; i < 4; ++i) {
                const int r = m0 + wid * 32 + mf * 16 + lg * 4 + i;
                if (r < M) {
                    const float v = acc[mf][nf][i]
                                  + sw_pos[r] * bpv + sw_neg[r] * bnv + bsv;
                    out[(size_t)r * 256 + col] = fmaxf(v, 0.f);
                }
            }
        }
    }
}

// ---------------------------------------------------------------------------
// GEMM: C[M,N] = A[M,K] @ B[K,N] (fp32) — U = emb @ W_u
// ---------------------------------------------------------------------------
__global__ __launch_bounds__(256) void gemm_nn(
    const float* __restrict__ A, const float* __restrict__ B,
    float* __restrict__ C, int M, int N, int K)
{
    __shared__ float Ast[16][68];
    __shared__ float Bs[16][68];
    const int tid = threadIdx.x;
    const int tx = tid & 15, ty = tid >> 4;
    const int m0 = blockIdx.x * 64, n0 = blockIdx.y * 64;

    const int lm = tid >> 2;
    const int lk = (tid & 3) << 2;
    const int bk = tid >> 4;
    const int bn = (tid & 15) << 2;

    float acc[4][4] = {};

    for (int k0 = 0; k0 < K; k0 += 16) {
        float4 av = make_float4(0.f, 0.f, 0.f, 0.f);
        const int am = m0 + lm;
        if (am < M) av = *(const float4*)&A[(size_t)am * K + k0 + lk];
        const float4 bvl = *(const float4*)&B[(size_t)(k0 + bk) * N + n0 + bn];
        __syncthreads();
        Ast[lk + 0][lm] = av.x; Ast[lk + 1][lm] = av.y;
        Ast[lk + 2][lm] = av.z; Ast[lk + 3][lm] = av.w;
        *(float4*)&Bs[bk][bn] = bvl;
        __syncthreads();
#pragma unroll
        for (int k = 0; k < 16; ++k) {
            const float4 a = *(const float4*)&Ast[k][ty * 4];
            const float4 b = *(const float4*)&Bs[k][tx * 4];
            acc[0][0] += a.x * b.x; acc[0][1] += a.x * b.y; acc[0][2] += a.x * b.z; acc[0][3] += a.x * b.w;
            acc[1][0] += a.y * b.x; acc[1][1] += a.y * b.y; acc[1][2] += a.y * b.z; acc[1][3] += a.y * b.w;
            acc[2][0] += a.z * b.x; acc[2][1] += a.z * b.y; acc[2][2] += a.z * b.z; acc[2][3] += a.z * b.w;
            acc[3][0] += a.w * b.x; acc[3][1] += a.w * b.y; acc[3][2] += a.w * b.z; acc[3][3] += a.w * b.w;
        }
    }

#pragma unroll
    for (int i = 0; i < 4; ++i) {
        const int m = m0 + ty * 4 + i;
        if (m < M) {
            float4 o;
            o.x = acc[i][0]; o.y = acc[i][1]; o.z = acc[i][2]; o.w = acc[i][3];
            *(float4*)&C[(size_t)m * N + n0 + tx * 4] = o;
        }
    }
}

// ---------------------------------------------------------------------------
// Finsler edge weight, one wave per edge.
// ---------------------------------------------------------------------------
__global__ __launch_bounds__(256) void edge_weight(
    const float* __restrict__ emb, const float* __restrict__ U,
    const float* __restrict__ w_beta, const float* __restrict__ alpha_p,
    const int* __restrict__ src, const int* __restrict__ dst,
    float* __restrict__ w_out, int E)
{
    const int wv = (int)((blockIdx.x * (size_t)blockDim.x + threadIdx.x) >> 6);
    const int lane = threadIdx.x & 63;
    if (wv >= E) return;
    const int s = src[wv], d = dst[wv];

    const float* xj = emb + (size_t)s * EMBED;
    const float* xi = emb + (size_t)d * EMBED;
    const float* uj = U + (size_t)s * EMBED;

    const float xj0 = xj[lane], xj1 = xj[lane + 64];
    const float xi0 = xi[lane], xi1 = xi[lane + 64];
    const float u0 = uj[lane],  u1 = uj[lane + 64];
    const float wb0 = w_beta[lane], wb1 = w_beta[lane + 64];

    const float d0 = xi0 - xj0, d1 = xi1 - xj1;
    float pe = d0 * d0 + d1 * d1;
    float pa = d0 * u0 + d1 * u1;
    float pb = xj0 * wb0 + xj1 * wb1;

#pragma unroll
    for (int off = 32; off > 0; off >>= 1) {
        pe += __shfl_xor(pe, off);
        pa += __shfl_xor(pa, off);
        pb += __shfl_xor(pb, off);
    }

    if (lane == 0) {
        const float alpha = fminf(fmaxf(alpha_p[0], 0.1f), 10.0f);
        const float beta = tanhf(pb);
        const float dist = sqrtf(pe) + beta * pa;
        w_out[wv] = expf(-alpha * fmaxf(dist, 0.0f));
    }
}

// ---------------------------------------------------------------------------
// CSR-by-dst build: zero -> hist -> scan(3) -> place
// ---------------------------------------------------------------------------
__global__ __launch_bounds__(256) void zero_int(int* __restrict__ p, int n)
{
    const int i = blockIdx.x * blockDim.x + threadIdx.x;
    if (i < n) p[i] = 0;
}

__global__ __launch_bounds__(256) void hist(
    const int* __restrict__ dst, int* __restrict__ counts, int E)
{
    const int e = blockIdx.x * blockDim.x + threadIdx.x;
    if (e < E) atomicAdd(&counts[dst[e]], 1);
}

__global__ __launch_bounds__(256) void scan1(
    const int* __restrict__ counts, int* __restrict__ offs,
    int* __restrict__ bsum, int n)
{
    __shared__ int wsum[4];
    const int t = threadIdx.x;
    const int gi = blockIdx.x * 1024 + t * 4;
    int v[4];
#pragma unroll
    for (int j = 0; j < 4; ++j) v[j] = (gi + j < n) ? counts[gi + j] : 0;
    const int local = v[0] + v[1] + v[2] + v[3];
    const int lane = t & 63;
    int x = local;
#pragma unroll
    for (int off = 1; off < 64; off <<= 1) {
        const int y = __shfl_up(x, off);
        if (lane >= off) x += y;
    }
    if (lane == 63) wsum[t >> 6] = x;
    __syncthreads();
    int woff = 0;
    const int wid = t >> 6;
    for (int w = 0; w < wid; ++w) woff += wsum[w];
    int run = woff + x - local;
#pragma unroll
    for (int j = 0; j < 4; ++j) {
        if (gi + j < n) offs[gi + j] = run;
        run += v[j];
    }
    if (t == 255) bsum[blockIdx.x] = woff + x;
}

__global__ __launch_bounds__(128) void scan2(int* __restrict__ bsum, int nb)
{
    __shared__ int tmp[128];
    const int t = threadIdx.x;
    tmp[t] = (t < nb) ? bsum[t] : 0;
    __syncthreads();
    if (t < nb) {
        int s = 0;
        for (int i = 0; i < t; ++i) s += tmp[i];
        bsum[t] = s;
    }
}

__global__ __launch_bounds__(256) void scan3(
    int* __restrict__ offs, int* __restrict__ cur,
    const int* __restrict__ bsum, int n, int E)
{
    const int gi = blockIdx.x * blockDim.x + threadIdx.x;
    if (gi < n) {
        const int v = offs[gi] + bsum[gi >> 10];
        offs[gi] = v;
        cur[gi] = v;
    }
    if (gi == 0) offs[n] = E;
}

__global__ __launch_bounds__(256) void place(
    const int* __restrict__ src, const int* __restrict__ dst,
    const float* __restrict__ w, int* __restrict__ cur,
    int* __restrict__ esrc, float* __restrict__ ew, int E)
{
    const int e = blockIdx.x * blockDim.x + threadIdx.x;
    if (e < E) {
        const int p = atomicAdd(&cur[dst[e]], 1);
        esrc[p] = src[e];
        ew[p] = w[e];
    }
}

// ---------------------------------------------------------------------------
// Gather in h-space: agg[node] = sum_e w_e * h[src_e], sw[node] = sum_e w_e.
// ---------------------------------------------------------------------------
__global__ __launch_bounds__(256) void gather_h(
    const float* __restrict__ h, const int* __restrict__ offs,
    const int* __restrict__ esrc, const float* __restrict__ ew,
    float* __restrict__ agg, float* __restrict__ sw, int n)
{
    const int node = (int)((blockIdx.x * (size_t)blockDim.x + threadIdx.x) >> 6);
    const int lane = threadIdx.x & 63;
    if (node >= n) return;
    const int s0 = offs[node], s1 = offs[node + 1];

    float4 acc = make_float4(0.f, 0.f, 0.f, 0.f);
    float s = 0.f;
    for (int k = s0; k < s1; ++k) {
        const int sr = esrc[k];
        const float wv = ew[k];
        const float4 v = *(const float4*)&h[(size_t)sr * IN_DIM + lane * 4];
        acc.x += v.x * wv; acc.y += v.y * wv;
        acc.z += v.z * wv; acc.w += v.w * wv;
        s += wv;
    }

    *(float4*)&agg[(size_t)node * IN_DIM + lane * 4] = acc;
    if (lane == 0) sw[node] = s;
}

// ---------------------------------------------------------------------------
extern "C" void kernel_launch(void* const* d_in, const int* in_sizes, int n_in,
                              void* d_out, int out_size, void* d_ws, size_t ws_size,
                              hipStream_t stream)
{
    const float* h        = (const float*)d_in[0];
    const int*   pos_src  = (const int*)d_in[1];
    const int*   pos_dst  = (const int*)d_in[2];
    const int*   neg_src  = (const int*)d_in[3];
    const int*   neg_dst  = (const int*)d_in[4];
    const float* emb      = (const float*)d_in[5];
    const float* W_pos    = (const float*)d_in[6];
    const float* b_pos    = (const float*)d_in[7];
    const float* W_neg    = (const float*)d_in[8];
    const float* b_neg    = (const float*)d_in[9];
    const float* W_self   = (const float*)d_in[10];
    const float* b_self   = (const float*)d_in[11];
    const float* w_pos_b  = (const float*)d_in[12];
    const float* W_pos_u  = (const float*)d_in[13];
    const float* alpha_p  = (const float*)d_in[14];
    const float* w_neg_b  = (const float*)d_in[15];
    const float* W_neg_u  = (const float*)d_in[16];
    const float* alpha_n  = (const float*)d_in[17];
    float* out = (float*)d_out;

    const int n_nodes = in_sizes[0] / IN_DIM;   // 100000
    const int E       = in_sizes[1];            // 500000

    // Workspace layout.
    float* ws    = (float*)d_ws;
    float* aggP  = ws;                            // [N*256] (doubles as Ubuf)
    float* aggN  = aggP + (size_t)n_nodes * 256;  // [N*256]
    float* wpos  = aggN + (size_t)n_nodes * 256;  // [E]
    float* wneg  = wpos + E;                      // [E]
    float* swp   = wneg + E;                      // [N]
    float* swn   = swp + n_nodes;                 // [N]
    int*   counts = (int*)(swn + n_nodes);        // [N]
    int*   offs   = counts + n_nodes;             // [N+4]
    int*   cur    = offs + n_nodes + 4;           // [N]
    int*   bsum   = cur + n_nodes;                // [128]
    int*   esrc   = bsum + 128;                   // [E]
    float* ew     = (float*)(esrc + E);           // [E]
    _Float16* Whf = (_Float16*)(ew + E);          // [256*768] fp16
    float* Ubuf  = aggP;                          // phase-1 overlap

    const dim3 blk(256);
    const dim3 gU((n_nodes + 63) / 64, EMBED / 64);
    const dim3 gE((E + 3) / 4);                   // wave-per-edge
    const dim3 gEt((E + 255) / 256);              // thread-per-edge
    const dim3 gN((n_nodes + 255) / 256);         // thread-per-node
    const dim3 gW((n_nodes + 3) / 4);             // wave-per-node
    const dim3 gG((n_nodes + 127) / 128);         // mega-GEMM blocks (782)
    const int  nb = (n_nodes + 1023) / 1024;

    // --- Weight convert (tiny) ---
    conv_w_f16<<<768, blk, 0, stream>>>(W_pos, W_neg, W_self, Whf);

    // --- Phase 1: edge weights (Ubuf overlaps aggP; done before gathers) ---
    gemm_nn<<<gU, blk, 0, stream>>>(emb, W_pos_u, Ubuf, n_nodes, EMBED, EMBED);
    edge_weight<<<gE, blk, 0, stream>>>(emb, Ubuf, w_pos_b, alpha_p,
                                        pos_src, pos_dst, wpos, E);
    gemm_nn<<<gU, blk, 0, stream>>>(emb, W_neg_u, Ubuf, n_nodes, EMBED, EMBED);
    edge_weight<<<gE, blk, 0, stream>>>(emb, Ubuf, w_neg_b, alpha_n,
                                        neg_src, neg_dst, wneg, E);

    // --- Phase 2: pos CSR + gather into aggP/swp ---
    zero_int<<<gN, blk, 0, stream>>>(counts, n_nodes);
    hist<<<gEt, blk, 0, stream>>>(pos_dst, counts, E);
    scan1<<<nb, blk, 0, stream>>>(counts, offs, bsum, n_nodes);
    scan2<<<1, 128, 0, stream>>>(bsum, nb);
    scan3<<<gN, blk, 0, stream>>>(offs, cur, bsum, n_nodes, E);
    place<<<gEt, blk, 0, stream>>>(pos_src, pos_dst, wpos, cur, esrc, ew, E);
    gather_h<<<gW, blk, 0, stream>>>(h, offs, esrc, ew, aggP, swp, n_nodes);

    // --- Phase 3: neg CSR + gather into aggN/swn ---
    zero_int<<<gN, blk, 0, stream>>>(counts, n_nodes);
    hist<<<gEt, blk, 0, stream>>>(neg_dst, counts, E);
    scan1<<<nb, blk, 0, stream>>>(counts, offs, bsum, n_nodes);
    scan2<<<1, 128, 0, stream>>>(bsum, nb);
    scan3<<<gN, blk, 0, stream>>>(offs, cur, bsum, n_nodes, E);
    place<<<gEt, blk, 0, stream>>>(neg_src, neg_dst, wneg, cur, esrc, ew, E);
    gather_h<<<gW, blk, 0, stream>>>(h, offs, esrc, ew, aggN, swn, n_nodes);

    // --- Phase 4: tiled MFMA GEMM + bias + ReLU ---
    mega_gemm<<<gG, blk, 0, stream>>>(aggP, aggN, h, Whf,
                                      b_pos, b_neg, b_self, swp, swn,
                                      out, n_nodes);
}